// Round 7
// baseline (474.055 us; speedup 1.0000x reference)
//
#include <hip/hip_runtime.h>
#include <stdint.h>

// Problem: B=8, S=1024, V=8192, D=256. out[b,s,:] = (x[b,s,:] @ E)*16 + pos[s,:]*any(x[b,s,:])
// GEMM M=8192 K=8192 N=256, A=x (0/1), B=emb.
// R7: sequential pack pass x(int32,256MB) -> tiled byte A (64MB, LDS-image layout) + rowsums;
//     GEMM streams contiguous 64KB A-chunks via global_load_lds dbuf, unpacks bytes->bf16
//     in-register (2 int ops / bf16 pair), B fragment-major from L2. KSPLIT=8, no atomics.

#define K_TOT 8192
#define D_DIM 256
#define KSPLIT 8
#define KCHUNK 1024                 // k per block
#define PART_STRIDE (8192u * 256u)  // floats per partial

typedef short  short8  __attribute__((ext_vector_type(8)));
typedef float  floatx4 __attribute__((ext_vector_type(4)));
typedef int    intx4   __attribute__((ext_vector_type(4)));

union S8U { intx4 i; short8 s; };

// ws layout: [0,4MB)      bf16 B-table [c=16][kb=256][lane=64][8]
//            [4,68MB)     packed A: [mb=128][kb=8] chunks of 64KB; chunk = [tile=8][r=64][g'=16][8B]
//                         granule g' = g ^ (r&15); granule bytes k-order (0,2,1,3, 4,6,5,7)
//            [68,132MB)   fp32 partials [KSPLIT=8][8192][256]
//            [132MB,..)   int rs_part [KSPLIT=8][8192]
#define WS_PACK_OFF (4u * 1024u * 1024u)
#define WS_PART_OFF (68u * 1024u * 1024u)
#define WS_RS_OFF   (132u * 1024u * 1024u)

__device__ __forceinline__ unsigned int bf16_rne(float f) {
    unsigned int u = __float_as_uint(f);
    u += 0x7fffu + ((u >> 16) & 1u);
    return u >> 16;
}

__device__ __forceinline__ void load_lds16(const int* g, int* l) {
    __builtin_amdgcn_global_load_lds((const __attribute__((address_space(1))) unsigned int*)g,
                                     (__attribute__((address_space(3))) unsigned int*)l,
                                     16, 0, 0);
}

// ---- emb [8192][256] fp32 -> fragment-major bf16 table, scaled by sqrt(D)=16 ----
__global__ __launch_bounds__(256) void prep_kernel(const float* __restrict__ emb,
                                                   unsigned short* __restrict__ wsBf) {
    int gid = blockIdx.x * 256 + threadIdx.x;
    int l  = gid & 63;
    int kb = (gid >> 6) & 255;
    int c  = gid >> 14;
    int d  = c * 16 + (l & 15);
    int v0 = kb * 32 + (l >> 4) * 8;
    const float* src = emb + (size_t)v0 * D_DIM + d;
    intx4 q;
#pragma unroll
    for (int p = 0; p < 4; ++p) {
        unsigned int u0 = bf16_rne(src[(size_t)(2 * p) * D_DIM] * 16.0f);
        unsigned int u1 = bf16_rne(src[(size_t)(2 * p + 1) * D_DIM] * 16.0f);
        q[p] = (int)(u0 | (u1 << 16));
    }
    *(intx4*)(wsBf + (size_t)gid * 8) = q;
}

// ---- pack: x int32 -> tiled byte A + rowsums. Fully sequential 256MB read. ----
// grid (128 mb, 8 kb), 256 thr. Thread round j handles granule gid=j*256+t of the chunk:
// r = gid>>7, gk = gid&127 -> reads x[m0+r][kbeg+gk*8..+7] (32B), writes 8 permuted bytes.
__global__ __launch_bounds__(256) void pack_kernel(const int* __restrict__ x,
                                                   unsigned char* __restrict__ ap,
                                                   int* __restrict__ rsp) {
    __shared__ int rs[64];
    const int mb = blockIdx.x, kb = blockIdx.y;
    const int m0 = mb * 64, kbeg = kb * KCHUNK;
    const int t = threadIdx.x;
    if (t < 64) rs[t] = 0;
    __syncthreads();
    unsigned char* base = ap + ((size_t)(mb * KSPLIT + kb)) * 65536;
#pragma unroll 2
    for (int j = 0; j < 32; ++j) {
        int gid = j * 256 + t;
        int r  = gid >> 7;              // wave-uniform (128 consecutive gids per row)
        int gk = gid & 127;
        const int* src = x + (size_t)(m0 + r) * K_TOT + kbeg + gk * 8;
        intx4 a = *(const intx4*)src;
        intx4 b = *(const intx4*)(src + 4);
        uint2 w;                        // byte order (k0,k2,k1,k3) per 4-group
        w.x = (unsigned)(a[0] | (a[2] << 8) | (a[1] << 16) | (a[3] << 24));
        w.y = (unsigned)(b[0] | (b[2] << 8) | (b[1] << 16) | (b[3] << 24));
        int tl = gk >> 4, g = gk & 15;
        *(uint2*)(base + (size_t)tl * 8192 + r * 128 + ((g ^ (r & 15)) * 8)) = w;
        int s = a[0] + a[1] + a[2] + a[3] + b[0] + b[1] + b[2] + b[3];
        s += __shfl_xor(s, 1);  s += __shfl_xor(s, 2);  s += __shfl_xor(s, 4);
        s += __shfl_xor(s, 8);  s += __shfl_xor(s, 16); s += __shfl_xor(s, 32);
        if ((t & 63) == 0) atomicAdd(&rs[r], s);   // LDS atomic, 2-way contention
    }
    __syncthreads();
    if (t < 64) rsp[(size_t)kb * 8192 + m0 + t] = rs[t];
}

// ---- GEMM: grid (128 mb, 8 kidx), 256 thr = 4 waves (64-col slices), 64 rows/block ----
__global__ __launch_bounds__(256, 4) void gemm_kernel(const unsigned char* __restrict__ ap,
                                                      const unsigned short* __restrict__ wsBf,
                                                      float* __restrict__ part) {
    __shared__ unsigned char Al[2][8192];   // dbuf: tile = 64 rows x 128 k-bytes

    const int mb = blockIdx.x, kidx = blockIdx.y;
    const int m0 = mb * 64;
    const int t = threadIdx.x;
    const int wave = t >> 6, lane = t & 63;
    const int quad = lane >> 4, rl = lane & 15;

    const unsigned char* chunk = ap + ((size_t)(mb * KSPLIT + kidx)) * 65536;

    floatx4 acc[4][4];
#pragma unroll
    for (int i = 0; i < 4; ++i)
#pragma unroll
        for (int j = 0; j < 4; ++j) acc[i][j] = (floatx4){0.f, 0.f, 0.f, 0.f};

    // prologue: tile 0 (DMA is linear: LDS image == packed image)
    load_lds16((const int*)(chunk + t * 16), (int*)&Al[0][t * 16]);
    load_lds16((const int*)(chunk + 4096 + t * 16), (int*)&Al[0][4096 + t * 16]);

    const int kb0 = kidx * 32;              // global k32 base

    for (int tl = 0; tl < 8; ++tl) {
        __syncthreads();
        if (tl + 1 < 8) {
            const unsigned char* src = chunk + (size_t)(tl + 1) * 8192;
            unsigned char* dst = &Al[(tl + 1) & 1][0];
            load_lds16((const int*)(src + t * 16), (int*)(dst + t * 16));
            load_lds16((const int*)(src + 4096 + t * 16), (int*)(dst + 4096 + t * 16));
        }
        const unsigned char* buf = &Al[tl & 1][0];

#pragma unroll
        for (int s = 0; s < 4; ++s) {       // four k32 steps per tile
            const int kb = kb0 + tl * 4 + s;

            short8 af[4];
#pragma unroll
            for (int i = 0; i < 4; ++i) {
                int r = i * 16 + rl;
                int g = (s * 4 + quad) ^ rl;            // un-swizzle
                uint2 d = *(const uint2*)(buf + r * 128 + g * 8);
                S8U u;                                   // (b&0x10001)*0x3F80: 2 bf16/op
                u.i[0] = (int)((d.x & 0x00010001u) * 0x3F80u);
                u.i[1] = (int)(((d.x >> 8) & 0x00010001u) * 0x3F80u);
                u.i[2] = (int)((d.y & 0x00010001u) * 0x3F80u);
                u.i[3] = (int)(((d.y >> 8) & 0x00010001u) * 0x3F80u);
                af[i] = u.s;
            }

#pragma unroll
            for (int j = 0; j < 4; ++j) {   // B per-j to bound VGPR (4 waves/SIMD cap)
                short8 bf = ((const S8U*)(wsBf + ((size_t)((wave * 4 + j) * 256 + kb) * 64 + lane) * 8))->s;
#pragma unroll
                for (int i = 0; i < 4; ++i)
                    acc[i][j] = __builtin_amdgcn_mfma_f32_16x16x32_bf16(af[i], bf, acc[i][j], 0, 0, 0);
            }
        }
    }

    // partial store: C/D layout col=lane&15, row=quad*4+reg (m89-verified)
    float* pk = part + (size_t)kidx * PART_STRIDE;
#pragma unroll
    for (int i = 0; i < 4; ++i) {
#pragma unroll
        for (int j = 0; j < 4; ++j) {
            int col = wave * 64 + j * 16 + rl;
#pragma unroll
            for (int r = 0; r < 4; ++r) {
                int row = m0 + i * 16 + quad * 4 + r;
                pk[(size_t)row * D_DIM + col] = acc[i][j][r];
            }
        }
    }
}

// ---- reduce: out = sum_k part[k] + pos * (sum_k rs[k] > 0) ----
__global__ __launch_bounds__(256) void reduce_kernel(const float* __restrict__ part,
                                                     const int* __restrict__ rsp,
                                                     const float* __restrict__ pos,
                                                     float* __restrict__ out) {
    int gid = blockIdx.x * 256 + threadIdx.x;   // 512K threads, 4 floats each
    size_t base = (size_t)gid * 4;
    int row = gid >> 6;
    floatx4 a = *(const floatx4*)(part + base);
    int rsum = rsp[row];
#pragma unroll
    for (int k = 1; k < KSPLIT; ++k) {
        a += *(const floatx4*)(part + (size_t)k * PART_STRIDE + base);
        rsum += rsp[(size_t)k * 8192 + row];
    }
    if (rsum > 0) {
        int s = row & 1023;                      // m = b*1024 + s
        int col = (gid & 63) * 4;
        a += *(const floatx4*)(pos + (size_t)s * D_DIM + col);
    }
    *(floatx4*)(out + base) = a;
}

extern "C" void kernel_launch(void* const* d_in, const int* in_sizes, int n_in,
                              void* d_out, int out_size, void* d_ws, size_t ws_size,
                              hipStream_t stream) {
    const int*   x   = (const int*)d_in[0];     // [8,1024,8192] int32
    const float* emb = (const float*)d_in[1];   // [8192,256] fp32
    const float* pos = (const float*)d_in[2];   // [1,1024,256] fp32
    float*       out = (float*)d_out;           // [8,1024,256] fp32

    unsigned short* wsBf = (unsigned short*)d_ws;
    unsigned char*  apk  = (unsigned char*)d_ws + WS_PACK_OFF;
    float*          part = (float*)((char*)d_ws + WS_PART_OFF);
    int*            rsp  = (int*)((char*)d_ws + WS_RS_OFF);

    prep_kernel<<<dim3(1024), dim3(256), 0, stream>>>(emb, wsBf);
    pack_kernel<<<dim3(128, KSPLIT), dim3(256), 0, stream>>>(x, apk, rsp);
    gemm_kernel<<<dim3(128, KSPLIT), dim3(256), 0, stream>>>(apk, wsBf, part);
    reduce_kernel<<<dim3(2048), dim3(256), 0, stream>>>(part, rsp, pos, out);
}

// Round 8
// 426.731 us; speedup vs baseline: 1.1109x; 1.1109x over previous
//
#include <hip/hip_runtime.h>
#include <stdint.h>

// Problem: B=8, S=1024, V=8192, D=256. out[b,s,:] = (x[b,s,:] @ E)*16 + pos[s,:]*any(x[b,s,:])
// GEMM M=8192 K=8192 N=256, A=x (0/1 int32, 256 MB stream), B=emb (bf16 table in ws).
// R8: pure-m97 K-loop — BOTH A and B staged via global_load_lds (no regular global loads in
//     the loop, so no vmcnt cross-serialization of the DMA prefetch). BK=32, 48 KB LDS dbuf,
//     3 blocks/CU, KSPLIT=8, phase-rotated tile order, no atomics.

#define K_TOT 8192
#define D_DIM 256
#define KSPLIT 8
#define KCHUNK 1024                 // k per block
#define BK 32                       // ints of k per tile (= one k32 MFMA step)
#define NT 32                       // tiles per block
#define PART_STRIDE (8192u * 256u)  // floats per partial

typedef short  short8  __attribute__((ext_vector_type(8)));
typedef float  floatx4 __attribute__((ext_vector_type(4)));
typedef int    intx4   __attribute__((ext_vector_type(4)));

union S8U { intx4 i; short8 s; };

// ws layout: [0,4MB)     bf16 B-table [kb=256][cg=16][lane=64][8]  (16 KB contiguous per kb)
//            [4,68MB)    fp32 partials [KSPLIT=8][8192][256]
//            [68MB,..)   int rs_part [KSPLIT=8][8192]
#define WS_PART_OFF (4u * 1024u * 1024u)
#define WS_RS_OFF   (68u * 1024u * 1024u)

__device__ __forceinline__ unsigned int bf16_rne(float f) {
    unsigned int u = __float_as_uint(f);
    u += 0x7fffu + ((u >> 16) & 1u);
    return u >> 16;
}

__device__ __forceinline__ void load_lds16(const int* g, int* l) {
    __builtin_amdgcn_global_load_lds((const __attribute__((address_space(1))) unsigned int*)g,
                                     (__attribute__((address_space(3))) unsigned int*)l,
                                     16, 0, 0);
}

// ---- emb [8192][256] fp32 -> [kb][cg][lane][8] bf16 table, scaled by sqrt(D)=16 ----
// wsBt[((kb*16+c)*64+l)*8+jj] = bf16(emb[kb*32+(l>>4)*8+jj][c*16+(l&15)] * 16)
__global__ __launch_bounds__(256) void prep_kernel(const float* __restrict__ emb,
                                                   unsigned short* __restrict__ wsBt) {
    int gid = blockIdx.x * 256 + threadIdx.x;   // 256K threads, writes perfectly linear
    int l  = gid & 63;
    int c  = (gid >> 6) & 15;
    int kb = gid >> 10;
    int d  = c * 16 + (l & 15);
    int v0 = kb * 32 + (l >> 4) * 8;
    const float* src = emb + (size_t)v0 * D_DIM + d;
    intx4 q;
#pragma unroll
    for (int p = 0; p < 4; ++p) {
        unsigned int u0 = bf16_rne(src[(size_t)(2 * p) * D_DIM] * 16.0f);
        unsigned int u1 = bf16_rne(src[(size_t)(2 * p + 1) * D_DIM] * 16.0f);
        q[p] = (int)(u0 | (u1 << 16));
    }
    *(intx4*)(wsBt + (size_t)gid * 8) = q;
}

// ---- GEMM: grid (128 mb of 64 rows, KSPLIT=8), 256 thr = 4 waves (64-col slices) ----
// A LDS tile: row r (0..63), granule slot s (16B): holds source granule s^(r&7) [XOR swizzle]
// B LDS tile: [cg=16][lane=64][8 shorts] — exact DMA image of the wsBt kb-slice.
__global__ __launch_bounds__(256) void gemm_kernel(const int* __restrict__ x,
                                                   const unsigned short* __restrict__ wsBt,
                                                   float* __restrict__ part,
                                                   int* __restrict__ rsp) {
    __shared__ int   Al[2][2048];   // 2 x 8 KB  (64 rows x 32 ints)
    __shared__ short Bl[2][8192];   // 2 x 16 KB (one kb-slice: 32 k x 256 cols)

    const int mb = blockIdx.x, kidx = blockIdx.y;
    const int m0 = mb * 64;
    const int kbeg = kidx * KCHUNK;
    const int phase = (mb * 7 + kidx * 9) & (NT - 1);
    const int t = threadIdx.x;
    const int wave = t >> 6, lane = t & 63;
    const int quad = lane >> 4, rl = lane & 15;

    // A staging map: granule gi = p*256+t (p=0,1): row = gi>>3, slot = gi&7, src = slot^(row&7)
    const int arow = t >> 3, aslot = t & 7;
    const int asg  = aslot ^ (arow & 7);
    const int* gA = x + (size_t)(m0 + arow) * K_TOT + kbeg + asg * 4;  // +32*K_TOT for 2nd half

    const int kbase = kidx * NT;    // global k32-block base

    floatx4 acc[4][4];
#pragma unroll
    for (int i = 0; i < 4; ++i)
#pragma unroll
        for (int j = 0; j < 4; ++j) acc[i][j] = (floatx4){0.f, 0.f, 0.f, 0.f};
    int rp[4] = {0, 0, 0, 0};

    // prologue: stage tile p(0) into buf 0
    {
        const int p0 = phase;
        load_lds16(gA + p0 * BK, &Al[0][t * 4]);
        load_lds16(gA + (size_t)32 * K_TOT + p0 * BK, &Al[0][1024 + t * 4]);
        const unsigned short* bs = wsBt + (size_t)(kbase + p0) * 8192;
#pragma unroll
        for (int r = 0; r < 4; ++r)
            load_lds16((const int*)(bs + (r * 256 + t) * 8), (int*)&Bl[0][(r * 256 + t) * 8]);
    }

    for (int tl = 0; tl < NT; ++tl) {
        const int pcur = (tl + phase) & (NT - 1);
        __syncthreads();                 // DMA into buf[tl&1] done; prior readers of other buf done
        if (tl + 1 < NT) {
            const int pn = (tl + 1 + phase) & (NT - 1);
            const int b = (tl + 1) & 1;
            load_lds16(gA + pn * BK, &Al[b][t * 4]);
            load_lds16(gA + (size_t)32 * K_TOT + pn * BK, &Al[b][1024 + t * 4]);
            const unsigned short* bs = wsBt + (size_t)(kbase + pn) * 8192;
#pragma unroll
            for (int r = 0; r < 4; ++r)
                load_lds16((const int*)(bs + (r * 256 + t) * 8), (int*)&Bl[b][(r * 256 + t) * 8]);
        }
        const int cur = tl & 1;

        // B fragments from LDS (cg = wave*4+j): conflict-free b128 (2-way per 16-lane group)
        short8 bf[4];
#pragma unroll
        for (int j = 0; j < 4; ++j)
            bf[j] = *(const short8*)&Bl[cur][((wave * 4 + j) * 64 + lane) * 8];

        // A fragments: row = i*16+rl, source granules 2q,2q+1 at slots ^(row&7)
        short8 af[4];
#pragma unroll
        for (int i = 0; i < 4; ++i) {
            const int row = i * 16 + rl;
            const int* base = &Al[cur][row * 32];
            intx4 v0 = *(const intx4*)(base + (((quad * 2)     ^ (row & 7)) * 4));
            intx4 v1 = *(const intx4*)(base + (((quad * 2 + 1) ^ (row & 7)) * 4));
            int p0 = v0[0] | (v0[1] << 16);
            int p1 = v0[2] | (v0[3] << 16);
            int p2 = v1[0] | (v1[1] << 16);
            int p3 = v1[2] | (v1[3] << 16);
            if (wave == 0) rp[i] += p0 + p1 + p2 + p3;   // packed 0/1 pair counts
            S8U u;
            u.i[0] = p0 * 0x3F80;       // pair * 0x3F80 -> two bf16 (1.0/0.0)
            u.i[1] = p1 * 0x3F80;
            u.i[2] = p2 * 0x3F80;
            u.i[3] = p3 * 0x3F80;
            af[i] = u.s;
        }

#pragma unroll
        for (int i = 0; i < 4; ++i)
#pragma unroll
            for (int j = 0; j < 4; ++j)
                acc[i][j] = __builtin_amdgcn_mfma_f32_16x16x32_bf16(af[i], bf[j], acc[i][j], 0, 0, 0);
    }

    // row-sums (wave 0's lanes jointly saw every (row,k) of the chunk): reduce quads, store
    if (wave == 0) {
#pragma unroll
        for (int i = 0; i < 4; ++i) {
            int cnt = (rp[i] & 0xFFFF) + ((unsigned)rp[i] >> 16);
            cnt += __shfl_xor(cnt, 16);
            cnt += __shfl_xor(cnt, 32);
            if (quad == 0) rsp[(size_t)kidx * 8192 + m0 + i * 16 + rl] = cnt;
        }
    }

    // partial store: C/D layout col=lane&15, row=quad*4+reg (m89-verified)
    float* pk = part + (size_t)kidx * PART_STRIDE;
#pragma unroll
    for (int i = 0; i < 4; ++i) {
#pragma unroll
        for (int j = 0; j < 4; ++j) {
            int col = wave * 64 + j * 16 + rl;
#pragma unroll
            for (int r = 0; r < 4; ++r) {
                int row = m0 + i * 16 + quad * 4 + r;
                pk[(size_t)row * D_DIM + col] = acc[i][j][r];
            }
        }
    }
}

// ---- reduce: out = sum_k part[k] + pos * (sum_k rs[k] > 0) ----
__global__ __launch_bounds__(256) void reduce_kernel(const float* __restrict__ part,
                                                     const int* __restrict__ rsp,
                                                     const float* __restrict__ pos,
                                                     float* __restrict__ out) {
    int gid = blockIdx.x * 256 + threadIdx.x;   // 512K threads, 4 floats each
    size_t base = (size_t)gid * 4;
    int row = gid >> 6;
    floatx4 a = *(const floatx4*)(part + base);
    int rsum = rsp[row];
#pragma unroll
    for (int k = 1; k < KSPLIT; ++k) {
        a += *(const floatx4*)(part + (size_t)k * PART_STRIDE + base);
        rsum += rsp[(size_t)k * 8192 + row];
    }
    if (rsum > 0) {
        int s = row & 1023;                      // m = b*1024 + s
        int col = (gid & 63) * 4;
        a += *(const floatx4*)(pos + (size_t)s * D_DIM + col);
    }
    *(floatx4*)(out + base) = a;
}

extern "C" void kernel_launch(void* const* d_in, const int* in_sizes, int n_in,
                              void* d_out, int out_size, void* d_ws, size_t ws_size,
                              hipStream_t stream) {
    const int*   x   = (const int*)d_in[0];     // [8,1024,8192] int32
    const float* emb = (const float*)d_in[1];   // [8192,256] fp32
    const float* pos = (const float*)d_in[2];   // [1,1024,256] fp32
    float*       out = (float*)d_out;           // [8,1024,256] fp32

    unsigned short* wsBt = (unsigned short*)d_ws;
    float*          part = (float*)((char*)d_ws + WS_PART_OFF);
    int*            rsp  = (int*)((char*)d_ws + WS_RS_OFF);

    prep_kernel<<<dim3(1024), dim3(256), 0, stream>>>(emb, wsBt);
    gemm_kernel<<<dim3(128, KSPLIT), dim3(256), 0, stream>>>(x, wsBt, part, rsp);
    reduce_kernel<<<dim3(2048), dim3(256), 0, stream>>>(part, rsp, pos, out);
}

// Round 9
// 394.912 us; speedup vs baseline: 1.2004x; 1.0806x over previous
//
#include <hip/hip_runtime.h>
#include <stdint.h>

// Problem: B=8, S=1024, V=8192, D=256. out[b,s,:] = (x[b,s,:] @ E)*16 + pos[s,:]*any(x[b,s,:])
// GEMM M=8192 K=8192 N=256, A=x (0/1 int32, 256 MB stream), B=emb (bf16 table in ws).
// R9: R6 verbatim + cache policy: A-DMA non-temporal (aux=NT, don't thrash L2 with the
//     read-once stream) and non-temporal partial stores, so the 4 MB B-table stays
//     L2-resident per XCD. Pure A/B test of the L2-thrash/L3-bandwidth theory.

#define K_TOT 8192
#define D_DIM 256
#define KSPLIT 4
#define KCHUNK (K_TOT / KSPLIT)   // 2048
#define BK 64                     // ints of k per tile (256 B per row = 1 interleave granule)
#define TROWS 32                  // rows per block
#define NTILES (KCHUNK / BK)      // 32
#define PART_STRIDE (8192u * 256u)  // floats per partial

typedef short  short8  __attribute__((ext_vector_type(8)));
typedef float  floatx4 __attribute__((ext_vector_type(4)));
typedef int    intx4   __attribute__((ext_vector_type(4)));

union S8U { intx4 i; short8 s; };

// ws layout: [0,4MB) bf16 B-table [c=16][kb=256][lane=64][8]
//            [4MB, 36MB) fp32 partials [KSPLIT][8192][256]
//            [36MB, +32KB*4) int rs_part [KSPLIT][8192]
#define WS_PART_OFF (4u * 1024u * 1024u)
#define WS_RS_OFF   (36u * 1024u * 1024u)

__device__ __forceinline__ unsigned int bf16_rne(float f) {
    unsigned int u = __float_as_uint(f);
    u += 0x7fffu + ((u >> 16) & 1u);
    return u >> 16;
}

// aux=2 -> NT/SLC: non-temporal, minimize L2 pollution from the read-once A stream
__device__ __forceinline__ void load_lds16_nt(const int* g, int* l) {
    __builtin_amdgcn_global_load_lds((const __attribute__((address_space(1))) unsigned int*)g,
                                     (__attribute__((address_space(3))) unsigned int*)l,
                                     16, 0, 2);
}

// ---- emb [8192][256] fp32 -> fragment-major bf16 table, scaled by sqrt(D)=16 ----
// wsBf[((c*256+kb)*64+l)*8+jj] = bf16(emb[kb*32+(l>>4)*8+jj][c*16+(l&15)] * 16)
__global__ __launch_bounds__(256) void prep_kernel(const float* __restrict__ emb,
                                                   unsigned short* __restrict__ wsBf) {
    int gid = blockIdx.x * 256 + threadIdx.x;
    int l  = gid & 63;
    int kb = (gid >> 6) & 255;
    int c  = gid >> 14;
    int d  = c * 16 + (l & 15);
    int v0 = kb * 32 + (l >> 4) * 8;
    const float* src = emb + (size_t)v0 * D_DIM + d;
    intx4 q;
#pragma unroll
    for (int p = 0; p < 4; ++p) {
        unsigned int u0 = bf16_rne(src[(size_t)(2 * p) * D_DIM] * 16.0f);
        unsigned int u1 = bf16_rne(src[(size_t)(2 * p + 1) * D_DIM] * 16.0f);
        q[p] = (int)(u0 | (u1 << 16));
    }
    *(intx4*)(wsBf + (size_t)gid * 8) = q;
}

// ---- GEMM: grid (256 m-blocks of 32 rows, KSPLIT=4), 256 thr = 4 waves (64-col slices) ----
// LDS tile layout: 16B slot s (s=0..511): row = s>>4, granule (s&15)^(row&7)  [XOR swizzle]
// K-tiles visited in rotated order p(tl) = (tl + phase) & 31  [channel decamping]
__global__ __launch_bounds__(256) void gemm_kernel(const int* __restrict__ x,
                                                   const unsigned short* __restrict__ wsBf,
                                                   float* __restrict__ part,
                                                   int* __restrict__ rsp) {
    __shared__ int Al[2][2048];    // 2 x 8KB (32 rows x 64 ints)

    const int m0    = blockIdx.x * TROWS;
    const int kidx  = blockIdx.y;
    const int kbeg  = kidx * KCHUNK;
    const int phase = (blockIdx.x * 7 + blockIdx.y * 9) & (NTILES - 1);
    const int t     = threadIdx.x;
    const int wave  = t >> 6, lane = t & 63;
    const int quad  = lane >> 4, rl = lane & 15;
    const int sx    = rl & 7;                   // read-side swizzle key

    // staging: slot t = rows 0..15, slot 256+t = rows 16..31 (same k-offset per lane)
    const int row0 = t >> 4;
    const int kof  = (t & 15) ^ (row0 & 7);
    const int* g0 = x + (size_t)(m0 + row0) * K_TOT + kbeg + kof * 4;
    const int* g1 = g0 + (size_t)16 * K_TOT;

    floatx4 acc[2][4];
#pragma unroll
    for (int i = 0; i < 2; ++i)
#pragma unroll
        for (int j = 0; j < 4; ++j) acc[i][j] = (floatx4){0.f, 0.f, 0.f, 0.f};
    int rp[2] = {0, 0};

    const int kbase = kidx * (KCHUNK / 32);     // global 32-int k-block base

    // prologue: stage tile p(0) into buf 0
    load_lds16_nt(g0 + phase * BK, &Al[0][t * 4]);
    load_lds16_nt(g1 + phase * BK, &Al[0][1024 + t * 4]);

    for (int tl = 0; tl < NTILES; ++tl) {
        const int pcur = (tl + phase) & (NTILES - 1);
        __syncthreads();                         // buf[tl&1] ready; prior readers done
        if (tl + 1 < NTILES) {
            const int pnx = (tl + 1 + phase) & (NTILES - 1);
            const int* ga = g0 + pnx * BK;
            const int* gb = g1 + pnx * BK;
            int* dst = &Al[(tl + 1) & 1][0];
            load_lds16_nt(ga, dst + t * 4);
            load_lds16_nt(gb, dst + 1024 + t * 4);
        }
        const int* buf = &Al[tl & 1][0];

#pragma unroll
        for (int s = 0; s < 2; ++s) {            // two k32 steps per tile
            const int kb = kbase + pcur * 2 + s;

            short8 bf[4];                        // B: cacheable globals (want L2-resident)
#pragma unroll
            for (int j = 0; j < 4; ++j)
                bf[j] = ((const S8U*)(wsBf + ((size_t)((wave * 4 + j) * 256 + kb) * 64 + lane) * 8))->s;

            short8 af[2];
#pragma unroll
            for (int i = 0; i < 2; ++i) {
                int ka = (s * 8 + quad * 2) ^ sx;        // slot of ints k..k+3
                int kc = (s * 8 + quad * 2 + 1) ^ sx;    // slot of ints k+4..k+7
                int rowb = (i * 16 + rl) * 16;
                intx4 v0 = *(const intx4*)(buf + (rowb + ka) * 4);
                intx4 v1 = *(const intx4*)(buf + (rowb + kc) * 4);
                int p0 = v0[0] | (v0[1] << 16);
                int p1 = v0[2] | (v0[3] << 16);
                int p2 = v1[0] | (v1[1] << 16);
                int p3 = v1[2] | (v1[3] << 16);
                if (wave == 0) rp[i] += p0 + p1 + p2 + p3;
                S8U u;
                u.i[0] = p0 * 0x3F80;                    // pair*0x3F80 -> two bf16 (1.0/0.0)
                u.i[1] = p1 * 0x3F80;
                u.i[2] = p2 * 0x3F80;
                u.i[3] = p3 * 0x3F80;
                af[i] = u.s;
            }

#pragma unroll
            for (int i = 0; i < 2; ++i)
#pragma unroll
                for (int j = 0; j < 4; ++j)
                    acc[i][j] = __builtin_amdgcn_mfma_f32_16x16x32_bf16(af[i], bf[j], acc[i][j], 0, 0, 0);
        }
    }

    // row-sums (wave 0 saw every A element): reduce quads, store per-block (no atomics)
    if (wave == 0) {
#pragma unroll
        for (int i = 0; i < 2; ++i) {
            int cnt = (rp[i] & 0xFFFF) + ((unsigned)rp[i] >> 16);
            cnt += __shfl_xor(cnt, 16);
            cnt += __shfl_xor(cnt, 32);
            if (quad == 0) rsp[(size_t)kidx * 8192 + m0 + i * 16 + rl] = cnt;
        }
    }

    // partial store: C/D layout col=lane&15, row=quad*4+reg (m89-verified).
    // Non-temporal: write-once data, don't evict the B-table from L2.
    float* pk = part + (size_t)kidx * PART_STRIDE;
#pragma unroll
    for (int i = 0; i < 2; ++i) {
#pragma unroll
        for (int j = 0; j < 4; ++j) {
            int col = wave * 64 + j * 16 + rl;
#pragma unroll
            for (int r = 0; r < 4; ++r) {
                int row = m0 + i * 16 + quad * 4 + r;
                __builtin_nontemporal_store(acc[i][j][r], &pk[(size_t)row * D_DIM + col]);
            }
        }
    }
}

// ---- reduce: out = sum_k part[k] + pos * (sum_k rs[k] > 0) ----
__global__ __launch_bounds__(256) void reduce_kernel(const float* __restrict__ part,
                                                     const int* __restrict__ rsp,
                                                     const float* __restrict__ pos,
                                                     float* __restrict__ out) {
    int gid = blockIdx.x * 256 + threadIdx.x;    // 512K threads, 4 floats each
    size_t base = (size_t)gid * 4;
    int row = gid >> 6;
    floatx4 a = *(const floatx4*)(part + base);
    int rsum = rsp[row];
#pragma unroll
    for (int k = 1; k < KSPLIT; ++k) {
        a += *(const floatx4*)(part + (size_t)k * PART_STRIDE + base);
        rsum += rsp[(size_t)k * 8192 + row];
    }
    if (rsum > 0) {
        int s = row & 1023;
        int col = (gid & 63) * 4;
        a += *(const floatx4*)(pos + (size_t)s * D_DIM + col);
    }
    *(floatx4*)(out + base) = a;
}

extern "C" void kernel_launch(void* const* d_in, const int* in_sizes, int n_in,
                              void* d_out, int out_size, void* d_ws, size_t ws_size,
                              hipStream_t stream) {
    const int*   x   = (const int*)d_in[0];     // [8,1024,8192] int32
    const float* emb = (const float*)d_in[1];   // [8192,256] fp32
    const float* pos = (const float*)d_in[2];   // [1,1024,256] fp32
    float*       out = (float*)d_out;           // [8,1024,256] fp32

    unsigned short* wsBf = (unsigned short*)d_ws;
    float*          part = (float*)((char*)d_ws + WS_PART_OFF);
    int*            rsp  = (int*)((char*)d_ws + WS_RS_OFF);

    prep_kernel<<<dim3(1024), dim3(256), 0, stream>>>(emb, wsBf);
    gemm_kernel<<<dim3(256, KSPLIT), dim3(256), 0, stream>>>(x, wsBf, part, rsp);
    reduce_kernel<<<dim3(2048), dim3(256), 0, stream>>>(part, rsp, pos, out);
}

// Round 11
// 389.006 us; speedup vs baseline: 1.2186x; 1.0152x over previous
//
#include <hip/hip_runtime.h>
#include <stdint.h>

// Problem: B=8, S=1024, V=8192, D=256. out[b,s,:] = (x[b,s,:] @ E)*16 + pos[s,:]*any(x[b,s,:])
// GEMM M=8192 K=8192 N=256, A=x (0/1 int32, 256 MB stream), B=emb (bf16 table in ws).
// R11: R10 (BK=128, 16 KB A-tile per barrier round) with a DMA-LEGAL staging map:
//      each global_load_lds wave-op writes 64 consecutive 16B granules (base + lane*16B),
//      covering exactly 2 rows. R10's map scattered (t>>4)*128+(t&15)*4 and corrupted LDS.
//      NT A-loads + NT partial stores, phase rotation, XOR swizzle, no atomics.

#define K_TOT 8192
#define D_DIM 256
#define KSPLIT 4
#define KCHUNK (K_TOT / KSPLIT)   // 2048
#define BK 128                    // ints of k per tile (512 B per row)
#define TROWS 32                  // rows per block
#define NTILES (KCHUNK / BK)      // 16
#define PART_STRIDE (8192u * 256u)  // floats per partial

typedef short  short8  __attribute__((ext_vector_type(8)));
typedef float  floatx4 __attribute__((ext_vector_type(4)));
typedef int    intx4   __attribute__((ext_vector_type(4)));

union S8U { intx4 i; short8 s; };

// ws layout: [0,4MB) bf16 B-table [c=16][kb=256][lane=64][8]
//            [4MB, 36MB) fp32 partials [KSPLIT][8192][256]
//            [36MB, +32KB*4) int rs_part [KSPLIT][8192]
#define WS_PART_OFF (4u * 1024u * 1024u)
#define WS_RS_OFF   (36u * 1024u * 1024u)

__device__ __forceinline__ unsigned int bf16_rne(float f) {
    unsigned int u = __float_as_uint(f);
    u += 0x7fffu + ((u >> 16) & 1u);
    return u >> 16;
}

// aux=2 -> NT: read-once stream, minimize L2 pollution
__device__ __forceinline__ void load_lds16_nt(const int* g, int* l) {
    __builtin_amdgcn_global_load_lds((const __attribute__((address_space(1))) unsigned int*)g,
                                     (__attribute__((address_space(3))) unsigned int*)l,
                                     16, 0, 2);
}

// ---- emb [8192][256] fp32 -> fragment-major bf16 table, scaled by sqrt(D)=16 ----
// wsBf[((c*256+kb)*64+l)*8+jj] = bf16(emb[kb*32+(l>>4)*8+jj][c*16+(l&15)] * 16)
__global__ __launch_bounds__(256) void prep_kernel(const float* __restrict__ emb,
                                                   unsigned short* __restrict__ wsBf) {
    int gid = blockIdx.x * 256 + threadIdx.x;
    int l  = gid & 63;
    int kb = (gid >> 6) & 255;
    int c  = gid >> 14;
    int d  = c * 16 + (l & 15);
    int v0 = kb * 32 + (l >> 4) * 8;
    const float* src = emb + (size_t)v0 * D_DIM + d;
    intx4 q;
#pragma unroll
    for (int p = 0; p < 4; ++p) {
        unsigned int u0 = bf16_rne(src[(size_t)(2 * p) * D_DIM] * 16.0f);
        unsigned int u1 = bf16_rne(src[(size_t)(2 * p + 1) * D_DIM] * 16.0f);
        q[p] = (int)(u0 | (u1 << 16));
    }
    *(intx4*)(wsBf + (size_t)gid * 8) = q;
}

// ---- GEMM: grid (256 m-blocks of 32 rows, KSPLIT=4), 256 thr = 4 waves (64-col slices) ----
// LDS tile image: granule G (16B), G = row*32 + slot; holds A granule slot^(row&7) of row.
// Staging: wave w, load p covers granules [w*256+p*64, +64) = rows w*8+2p, w*8+2p+1.
// K-tiles visited rotated: p(tl) = (tl+phase) & 15.
__global__ __launch_bounds__(256) void gemm_kernel(const int* __restrict__ x,
                                                   const unsigned short* __restrict__ wsBf,
                                                   float* __restrict__ part,
                                                   int* __restrict__ rsp) {
    __shared__ int Al[2][4096];    // 2 x 16 KB (32 rows x 128 ints)

    const int m0    = blockIdx.x * TROWS;
    const int kidx  = blockIdx.y;
    const int kbeg  = kidx * KCHUNK;
    const int phase = (blockIdx.x * 7 + blockIdx.y * 9) & (NTILES - 1);
    const int t     = threadIdx.x;
    const int wave  = t >> 6, lane = t & 63;
    const int quad  = lane >> 4, rl = lane & 15;
    const int sx    = rl & 7;                   // read-side swizzle key

    // staging map (DMA-legal): wave `wave`, load p -> row = wave*8 + 2p + (lane>>5),
    // slot = lane&31, source granule = slot ^ (row&7), dest granule = wave*256 + p*64 + lane.
    const int srow0 = wave * 8 + (lane >> 5);   // row for p=0
    const int slt   = lane & 31;
    const int* gsrc[4];
#pragma unroll
    for (int p = 0; p < 4; ++p) {
        int rw = srow0 + 2 * p;
        gsrc[p] = x + (size_t)(m0 + rw) * K_TOT + kbeg + ((slt ^ (rw & 7)) * 4);
    }
    const int dofs = (wave * 256 + lane) * 4;   // + p*256 ints per load

    floatx4 acc[2][4];
#pragma unroll
    for (int i = 0; i < 2; ++i)
#pragma unroll
        for (int j = 0; j < 4; ++j) acc[i][j] = (floatx4){0.f, 0.f, 0.f, 0.f};
    int rp[2] = {0, 0};

    const int kbase = kidx * (KCHUNK / 32);     // global 32-int k-block base

    // prologue: stage tile p(0) into buf 0
#pragma unroll
    for (int p = 0; p < 4; ++p)
        load_lds16_nt(gsrc[p] + phase * BK, &Al[0][dofs + p * 256]);

    for (int tl = 0; tl < NTILES; ++tl) {
        const int pcur = (tl + phase) & (NTILES - 1);
        __syncthreads();                         // buf[tl&1] ready; prior readers done
        if (tl + 1 < NTILES) {
            const int pnx = (tl + 1 + phase) & (NTILES - 1);
            int* dst = &Al[(tl + 1) & 1][dofs];
#pragma unroll
            for (int p = 0; p < 4; ++p)
                load_lds16_nt(gsrc[p] + pnx * BK, dst + p * 256);
        }
        const int* buf = &Al[tl & 1][0];

#pragma unroll
        for (int s = 0; s < 4; ++s) {            // four k32 steps per tile
            const int kb = kbase + pcur * 4 + s;

            short8 bf[4];                        // B: cacheable (want L2-resident)
#pragma unroll
            for (int j = 0; j < 4; ++j)
                bf[j] = ((const S8U*)(wsBf + ((size_t)((wave * 4 + j) * 256 + kb) * 64 + lane) * 8))->s;

            short8 af[2];
#pragma unroll
            for (int i = 0; i < 2; ++i) {
                int g0 = s * 8 + quad * 2;               // granules for k..k+3, k+4..k+7
                int rowb = (i * 16 + rl) * 128;
                intx4 v0 = *(const intx4*)(buf + rowb + ((g0 ^ sx) * 4));
                intx4 v1 = *(const intx4*)(buf + rowb + (((g0 + 1) ^ sx) * 4));
                int p0 = v0[0] | (v0[1] << 16);
                int p1 = v0[2] | (v0[3] << 16);
                int p2 = v1[0] | (v1[1] << 16);
                int p3 = v1[2] | (v1[3] << 16);
                if (wave == 0) rp[i] += p0 + p1 + p2 + p3;
                S8U u;
                u.i[0] = p0 * 0x3F80;                    // pair*0x3F80 -> two bf16 (1.0/0.0)
                u.i[1] = p1 * 0x3F80;
                u.i[2] = p2 * 0x3F80;
                u.i[3] = p3 * 0x3F80;
                af[i] = u.s;
            }

#pragma unroll
            for (int i = 0; i < 2; ++i)
#pragma unroll
                for (int j = 0; j < 4; ++j)
                    acc[i][j] = __builtin_amdgcn_mfma_f32_16x16x32_bf16(af[i], bf[j], acc[i][j], 0, 0, 0);
        }
    }

    // row-sums (wave 0 saw every A element across its quads/s-steps): reduce, store
    if (wave == 0) {
#pragma unroll
        for (int i = 0; i < 2; ++i) {
            int cnt = (rp[i] & 0xFFFF) + ((unsigned)rp[i] >> 16);
            cnt += __shfl_xor(cnt, 16);
            cnt += __shfl_xor(cnt, 32);
            if (quad == 0) rsp[(size_t)kidx * 8192 + m0 + i * 16 + rl] = cnt;
        }
    }

    // partial store: C/D layout col=lane&15, row=quad*4+reg (m89-verified). NT stores.
    float* pk = part + (size_t)kidx * PART_STRIDE;
#pragma unroll
    for (int i = 0; i < 2; ++i) {
#pragma unroll
        for (int j = 0; j < 4; ++j) {
            int col = wave * 64 + j * 16 + rl;
#pragma unroll
            for (int r = 0; r < 4; ++r) {
                int row = m0 + i * 16 + quad * 4 + r;
                __builtin_nontemporal_store(acc[i][j][r], &pk[(size_t)row * D_DIM + col]);
            }
        }
    }
}

// ---- reduce: out = sum_k part[k] + pos * (sum_k rs[k] > 0) ----
__global__ __launch_bounds__(256) void reduce_kernel(const float* __restrict__ part,
                                                     const int* __restrict__ rsp,
                                                     const float* __restrict__ pos,
                                                     float* __restrict__ out) {
    int gid = blockIdx.x * 256 + threadIdx.x;    // 512K threads, 4 floats each
    size_t base = (size_t)gid * 4;
    int row = gid >> 6;
    floatx4 a = *(const floatx4*)(part + base);
    int rsum = rsp[row];
#pragma unroll
    for (int k = 1; k < KSPLIT; ++k) {
        a += *(const floatx4*)(part + (size_t)k * PART_STRIDE + base);
        rsum += rsp[(size_t)k * 8192 + row];
    }
    if (rsum > 0) {
        int s = row & 1023;
        int col = (gid & 63) * 4;
        a += *(const floatx4*)(pos + (size_t)s * D_DIM + col);
    }
    *(floatx4*)(out + base) = a;
}

extern "C" void kernel_launch(void* const* d_in, const int* in_sizes, int n_in,
                              void* d_out, int out_size, void* d_ws, size_t ws_size,
                              hipStream_t stream) {
    const int*   x   = (const int*)d_in[0];     // [8,1024,8192] int32
    const float* emb = (const float*)d_in[1];   // [8192,256] fp32
    const float* pos = (const float*)d_in[2];   // [1,1024,256] fp32
    float*       out = (float*)d_out;           // [8,1024,256] fp32

    unsigned short* wsBf = (unsigned short*)d_ws;
    float*          part = (float*)((char*)d_ws + WS_PART_OFF);
    int*            rsp  = (int*)((char*)d_ws + WS_RS_OFF);

    prep_kernel<<<dim3(1024), dim3(256), 0, stream>>>(emb, wsBf);
    gemm_kernel<<<dim3(256, KSPLIT), dim3(256), 0, stream>>>(x, wsBf, part, rsp);
    reduce_kernel<<<dim3(2048), dim3(256), 0, stream>>>(part, rsp, pos, out);
}

// Round 12
// 387.505 us; speedup vs baseline: 1.2234x; 1.0039x over previous
//
#include <hip/hip_runtime.h>
#include <stdint.h>

// Problem: B=8, S=1024, V=8192, D=256. out[b,s,:] = (x[b,s,:] @ E)*16 + pos[s,:]*any(x[b,s,:])
// GEMM M=8192 K=8192 N=256, A=x (0/1 int32, 256 MB stream), B=emb (bf16 table in ws).
// R12: single-variable test of the B-traffic wall. TROWS 32->64 (B re-reads 1 GB -> 512 MB),
//      BK=64 (same 16 KB/barrier round), KSPLIT=8 (grid 1024, 4 blocks/CU), bf16 partials.
//      Keeps R11's NT A-DMA, phase rotation, XOR swizzle, per-thread B loads, no atomics.

#define K_TOT 8192
#define D_DIM 256
#define KSPLIT 8
#define KCHUNK (K_TOT / KSPLIT)   // 1024
#define BK 64                     // ints of k per tile
#define TROWS 64                  // rows per block
#define NTILES (KCHUNK / BK)      // 16
#define PART_STRIDE (8192u * 256u)  // elements per partial

typedef short  short8  __attribute__((ext_vector_type(8)));
typedef float  floatx4 __attribute__((ext_vector_type(4)));
typedef int    intx4   __attribute__((ext_vector_type(4)));
typedef unsigned short ushort4v __attribute__((ext_vector_type(4)));

union S8U { intx4 i; short8 s; };

// ws layout: [0,4MB)    bf16 B-table [c=16][kb=256][lane=64][8]
//            [4,36MB)   bf16 partials [KSPLIT=8][8192][256]
//            [36MB,..)  int rs_part [KSPLIT=8][8192]
#define WS_PART_OFF (4u * 1024u * 1024u)
#define WS_RS_OFF   (36u * 1024u * 1024u)

__device__ __forceinline__ unsigned int bf16_rne(float f) {
    unsigned int u = __float_as_uint(f);
    u += 0x7fffu + ((u >> 16) & 1u);
    return u >> 16;
}

// aux=2 -> NT: read-once stream, minimize L2 pollution
__device__ __forceinline__ void load_lds16_nt(const int* g, int* l) {
    __builtin_amdgcn_global_load_lds((const __attribute__((address_space(1))) unsigned int*)g,
                                     (__attribute__((address_space(3))) unsigned int*)l,
                                     16, 0, 2);
}

// ---- emb [8192][256] fp32 -> fragment-major bf16 table, scaled by sqrt(D)=16 ----
// wsBf[((c*256+kb)*64+l)*8+jj] = bf16(emb[kb*32+(l>>4)*8+jj][c*16+(l&15)] * 16)
__global__ __launch_bounds__(256) void prep_kernel(const float* __restrict__ emb,
                                                   unsigned short* __restrict__ wsBf) {
    int gid = blockIdx.x * 256 + threadIdx.x;
    int l  = gid & 63;
    int kb = (gid >> 6) & 255;
    int c  = gid >> 14;
    int d  = c * 16 + (l & 15);
    int v0 = kb * 32 + (l >> 4) * 8;
    const float* src = emb + (size_t)v0 * D_DIM + d;
    intx4 q;
#pragma unroll
    for (int p = 0; p < 4; ++p) {
        unsigned int u0 = bf16_rne(src[(size_t)(2 * p) * D_DIM] * 16.0f);
        unsigned int u1 = bf16_rne(src[(size_t)(2 * p + 1) * D_DIM] * 16.0f);
        q[p] = (int)(u0 | (u1 << 16));
    }
    *(intx4*)(wsBf + (size_t)gid * 8) = q;
}

// ---- GEMM: grid (128 m-blocks of 64 rows, KSPLIT=8), 256 thr = 4 waves (64-col slices) ----
// LDS tile image: granule G (16B), G = row*16 + slot; holds A granule slot^(row&7) of row.
// Staging (DMA-legal): wave w, load p covers dest granules [w*256+p*64, +64) =
//   rows w*16+p*4 .. +3 (4 rows x 16 slots), dest = base + lane*16B.
// K-tiles visited rotated: p(tl) = (tl+phase) & 15.
__global__ __launch_bounds__(256, 4) void gemm_kernel(const int* __restrict__ x,
                                                      const unsigned short* __restrict__ wsBf,
                                                      unsigned short* __restrict__ part,
                                                      int* __restrict__ rsp) {
    __shared__ int Al[2][4096];    // 2 x 16 KB (64 rows x 64 ints)

    const int m0    = blockIdx.x * TROWS;
    const int kidx  = blockIdx.y;
    const int kbeg  = kidx * KCHUNK;
    const int phase = (blockIdx.x * 7 + blockIdx.y * 9) & (NTILES - 1);
    const int t     = threadIdx.x;
    const int wave  = t >> 6, lane = t & 63;
    const int quad  = lane >> 4, rl = lane & 15;
    const int sx    = rl & 7;                   // read-side swizzle key

    // staging map: wave w, load p: row = w*16 + p*4 + (lane>>4), slot = lane&15,
    // source granule = slot ^ (row&7), dest int offset = w*1024 + p*256 + lane*4.
    const int srow0 = wave * 16 + (lane >> 4);
    const int slt   = lane & 15;
    const int* gsrc[4];
#pragma unroll
    for (int p = 0; p < 4; ++p) {
        int rw = srow0 + p * 4;
        gsrc[p] = x + (size_t)(m0 + rw) * K_TOT + kbeg + ((slt ^ (rw & 7)) * 4);
    }
    const int dofs = wave * 1024 + lane * 4;

    floatx4 acc[4][4];
#pragma unroll
    for (int i = 0; i < 4; ++i)
#pragma unroll
        for (int j = 0; j < 4; ++j) acc[i][j] = (floatx4){0.f, 0.f, 0.f, 0.f};
    int rp[4] = {0, 0, 0, 0};

    const int kbase = kidx * (KCHUNK / 32);     // global 32-int k-block base

    // prologue: stage tile p(0) into buf 0
#pragma unroll
    for (int p = 0; p < 4; ++p)
        load_lds16_nt(gsrc[p] + phase * BK, &Al[0][dofs + p * 256]);

    for (int tl = 0; tl < NTILES; ++tl) {
        const int pcur = (tl + phase) & (NTILES - 1);
        __syncthreads();                         // buf[tl&1] ready; prior readers done
        if (tl + 1 < NTILES) {
            const int pnx = (tl + 1 + phase) & (NTILES - 1);
            int* dst = &Al[(tl + 1) & 1][dofs];
#pragma unroll
            for (int p = 0; p < 4; ++p)
                load_lds16_nt(gsrc[p] + pnx * BK, dst + p * 256);
        }
        const int* buf = &Al[tl & 1][0];

#pragma unroll
        for (int s = 0; s < 2; ++s) {            // two k32 steps per tile
            const int kb = kbase + pcur * 2 + s;

            short8 bf[4];                        // B: cacheable (want L2-resident)
#pragma unroll
            for (int j = 0; j < 4; ++j)
                bf[j] = ((const S8U*)(wsBf + ((size_t)((wave * 4 + j) * 256 + kb) * 64 + lane) * 8))->s;

            short8 af[4];
#pragma unroll
            for (int i = 0; i < 4; ++i) {
                int row  = i * 16 + rl;
                int rowb = row * 64;
                int g0   = s * 8 + quad * 2;             // granules for k..k+3, k+4..k+7
                intx4 v0 = *(const intx4*)(buf + rowb + ((g0 ^ sx) * 4));
                intx4 v1 = *(const intx4*)(buf + rowb + (((g0 + 1) ^ sx) * 4));
                int p0 = v0[0] | (v0[1] << 16);
                int p1 = v0[2] | (v0[3] << 16);
                int p2 = v1[0] | (v1[1] << 16);
                int p3 = v1[2] | (v1[3] << 16);
                if (wave == 0) rp[i] += p0 + p1 + p2 + p3;
                S8U u;
                u.i[0] = p0 * 0x3F80;                    // pair*0x3F80 -> two bf16 (1.0/0.0)
                u.i[1] = p1 * 0x3F80;
                u.i[2] = p2 * 0x3F80;
                u.i[3] = p3 * 0x3F80;
                af[i] = u.s;
            }

#pragma unroll
            for (int i = 0; i < 4; ++i)
#pragma unroll
                for (int j = 0; j < 4; ++j)
                    acc[i][j] = __builtin_amdgcn_mfma_f32_16x16x32_bf16(af[i], bf[j], acc[i][j], 0, 0, 0);
        }
    }

    // row-sums (wave 0's lanes jointly saw every (row,k) of the chunk): reduce quads, store
    if (wave == 0) {
#pragma unroll
        for (int i = 0; i < 4; ++i) {
            int cnt = (rp[i] & 0xFFFF) + ((unsigned)rp[i] >> 16);
            cnt += __shfl_xor(cnt, 16);
            cnt += __shfl_xor(cnt, 32);
            if (quad == 0) rsp[(size_t)kidx * 8192 + m0 + i * 16 + rl] = cnt;
        }
    }

    // partial store as bf16 (quantization ~0.06 absmax worst case vs 1.91 threshold).
    // C/D layout col=lane&15, row=quad*4+reg (m89-verified). NT stores.
    unsigned short* pk = part + (size_t)kidx * PART_STRIDE;
#pragma unroll
    for (int i = 0; i < 4; ++i) {
#pragma unroll
        for (int j = 0; j < 4; ++j) {
            int col = wave * 64 + j * 16 + rl;
#pragma unroll
            for (int r = 0; r < 4; ++r) {
                int row = m0 + i * 16 + quad * 4 + r;
                __builtin_nontemporal_store((unsigned short)bf16_rne(acc[i][j][r]),
                                            &pk[(size_t)row * D_DIM + col]);
            }
        }
    }
}

// ---- reduce: out = sum_k bf16(part[k]) + pos * (sum_k rs[k] > 0) ----
__global__ __launch_bounds__(256) void reduce_kernel(const unsigned short* __restrict__ part,
                                                     const int* __restrict__ rsp,
                                                     const float* __restrict__ pos,
                                                     float* __restrict__ out) {
    int gid = blockIdx.x * 256 + threadIdx.x;    // 512K threads, 4 elements each
    size_t base = (size_t)gid * 4;
    int row = gid >> 6;
    floatx4 a = {0.f, 0.f, 0.f, 0.f};
    int rsum = 0;
#pragma unroll
    for (int k = 0; k < KSPLIT; ++k) {
        ushort4v u = *(const ushort4v*)(part + (size_t)k * PART_STRIDE + base);
#pragma unroll
        for (int e = 0; e < 4; ++e)
            a[e] += __uint_as_float((unsigned int)u[e] << 16);
        rsum += rsp[(size_t)k * 8192 + row];
    }
    if (rsum > 0) {
        int s = row & 1023;                      // m = b*1024 + s
        int col = (gid & 63) * 4;
        a += *(const floatx4*)(pos + (size_t)s * D_DIM + col);
    }
    *(floatx4*)(out + base) = a;
}

extern "C" void kernel_launch(void* const* d_in, const int* in_sizes, int n_in,
                              void* d_out, int out_size, void* d_ws, size_t ws_size,
                              hipStream_t stream) {
    const int*   x   = (const int*)d_in[0];     // [8,1024,8192] int32
    const float* emb = (const float*)d_in[1];   // [8192,256] fp32
    const float* pos = (const float*)d_in[2];   // [1,1024,256] fp32
    float*       out = (float*)d_out;           // [8,1024,256] fp32

    unsigned short* wsBf = (unsigned short*)d_ws;
    unsigned short* part = (unsigned short*)((char*)d_ws + WS_PART_OFF);
    int*            rsp  = (int*)((char*)d_ws + WS_RS_OFF);

    prep_kernel<<<dim3(1024), dim3(256), 0, stream>>>(emb, wsBf);
    gemm_kernel<<<dim3(128, KSPLIT), dim3(256), 0, stream>>>(x, wsBf, part, rsp);
    reduce_kernel<<<dim3(2048), dim3(256), 0, stream>>>(part, rsp, pos, out);
}